// Round 2
// baseline (260110.376 us; speedup 1.0000x reference)
//
#include <hip/hip_runtime.h>
#include <cstddef>

#define NSTEP 4096

// All device pointers the step kernel needs, passed by value.
struct Params {
  const float* xn;        // (4096, 64) normalized input
  const float* w_ih[4];
  const float* w_hh[4];
  const float* b_ih[4];
  const float* b_hh[4];
  float* h[4];            // double buffers: h[l] holds 2*H_l floats, parity t&1
  float* c[4];            // single buffer per layer
  float* out;             // (4096, 256) flat
  int s;                  // launch index
};

// BatchNorm1d over timestep channels: per t, stats over (B=4, F=64) = 256 vals.
__global__ __launch_bounds__(256) void bn_kernel(const float* __restrict__ x,
                                                 const float* __restrict__ bn_w,
                                                 const float* __restrict__ bn_b,
                                                 float* __restrict__ xn)
{
  const int t   = blockIdx.x;        // 0..1023
  const int tid = threadIdx.x;       // 256 = B*F
  const int b   = tid >> 6;
  const int f   = tid & 63;
  const float v = x[((size_t)b * 1024 + t) * 64 + f];
  float s = v, ss = v * v;
  #pragma unroll
  for (int off = 32; off > 0; off >>= 1) {
    s  += __shfl_down(s, off);
    ss += __shfl_down(ss, off);
  }
  __shared__ float sh[8];
  const int w = tid >> 6;
  if ((tid & 63) == 0) { sh[w] = s; sh[4 + w] = ss; }
  __syncthreads();
  const float S    = sh[0] + sh[1] + sh[2] + sh[3];
  const float SS   = sh[4] + sh[5] + sh[6] + sh[7];
  const float mean = S * (1.0f / 256.0f);
  const float var  = SS * (1.0f / 256.0f) - mean * mean;  // biased, matches jnp.var
  const float inv  = rsqrtf(var + 1e-5f);
  const float scale = bn_w[t] * inv;
  const float shift = bn_b[t] - mean * scale;
  // scan order: step index = b*1024 + t
  xn[((size_t)b * 1024 + t) * 64 + f] = v * scale + shift;
}

// One launch = one pipeline slot: L1 does step s, L2 step s-1, L3 s-2, L4 s-3.
// One wave per h-index; the wave computes all 4 gate rows (i,f,g,o) for that
// h, reduces, and lane 0 applies activations + state update. No LDS needed.
__global__ __launch_bounds__(256) void step_kernel(Params p)
{
  const int lane = threadIdx.x & 63;
  const int W = blockIdx.x * 4 + (threadIdx.x >> 6);  // global wave id, 0..3839

  int layer, h, H, IN, t;
  if (W < 2048)      { layer = 0; h = W;        H = 2048; IN = 64;   t = p.s;     }
  else if (W < 3072) { layer = 1; h = W - 2048; H = 1024; IN = 2048; t = p.s - 1; }
  else if (W < 3584) { layer = 2; h = W - 3072; H = 512;  IN = 1024; t = p.s - 2; }
  else               { layer = 3; h = W - 3584; H = 256;  IN = 512;  t = p.s - 3; }
  if (t < 0 || t >= NSTEP) return;

  const float* xin;
  if (layer == 0) xin = p.xn + (size_t)t * 64;
  else            xin = p.h[layer - 1] + (size_t)(t & 1) * IN;  // prev layer, same step
  const float* hprev = p.h[layer] + (size_t)((t + 1) & 1) * H;  // own layer, step t-1
  float*       hout  = p.h[layer] + (size_t)(t & 1) * H;
  const float* wih = p.w_ih[layer];
  const float* whh = p.w_hh[layer];

  float acc[4];
  #pragma unroll
  for (int g = 0; g < 4; ++g) {
    const size_t r = (size_t)g * H + h;   // PyTorch gate order: i, f, g, o
    const float* wi = wih + r * IN;
    const float* wh = whh + r * (size_t)H;
    float a = 0.0f;
    for (int k = lane; k < IN; k += 64) a += wi[k] * xin[k];
    for (int k = lane; k < H;  k += 64) a += wh[k] * hprev[k];
    acc[g] = a;
  }
  #pragma unroll
  for (int off = 32; off > 0; off >>= 1) {
    #pragma unroll
    for (int g = 0; g < 4; ++g) acc[g] += __shfl_down(acc[g], off);
  }
  if (lane == 0) {
    const float* bi = p.b_ih[layer];
    const float* bh = p.b_hh[layer];
    const float gi = acc[0] + bi[h]         + bh[h];
    const float gf = acc[1] + bi[H + h]     + bh[H + h];
    const float gg = acc[2] + bi[2 * H + h] + bh[2 * H + h];
    const float go = acc[3] + bi[3 * H + h] + bh[3 * H + h];
    const float ig = 1.0f / (1.0f + expf(-gi));
    const float fg = 1.0f / (1.0f + expf(-gf));
    const float og = 1.0f / (1.0f + expf(-go));
    const float gt = tanhf(gg);
    const float cn = fg * p.c[layer][h] + ig * gt;
    const float hn = og * tanhf(cn);
    p.c[layer][h] = cn;
    hout[h] = hn;
    if (layer == 3) p.out[(size_t)t * 256 + h] = hn;
  }
}

extern "C" void kernel_launch(void* const* d_in, const int* in_sizes, int n_in,
                              void* d_out, int out_size, void* d_ws, size_t ws_size,
                              hipStream_t stream)
{
  Params p;
  const float* x    = (const float*)d_in[0];
  const float* bn_w = (const float*)d_in[1];
  const float* bn_b = (const float*)d_in[2];
  for (int l = 0; l < 4; ++l) {
    p.w_ih[l] = (const float*)d_in[3 + 4 * l];
    p.w_hh[l] = (const float*)d_in[4 + 4 * l];
    p.b_ih[l] = (const float*)d_in[5 + 4 * l];
    p.b_hh[l] = (const float*)d_in[6 + 4 * l];
  }

  float* ws = (float*)d_ws;
  float* xn = ws;                    // 4096*64 floats
  float* st = ws + (size_t)4096 * 64;
  p.xn = xn;
  const int Hs[4] = {2048, 1024, 512, 256};
  float* cur = st;
  for (int l = 0; l < 4; ++l) { p.h[l] = cur; cur += 2 * Hs[l]; }
  for (int l = 0; l < 4; ++l) { p.c[l] = cur; cur += Hs[l]; }
  p.out = (float*)d_out;

  const size_t state_bytes = (size_t)(cur - st) * sizeof(float);
  hipMemsetAsync(st, 0, state_bytes, stream);          // zero h/c each call

  bn_kernel<<<1024, 256, 0, stream>>>(x, bn_w, bn_b, xn);

  for (int s = 0; s < NSTEP + 3; ++s) {
    p.s = s;
    step_kernel<<<960, 256, 0, stream>>>(p);
  }
}

// Round 3
// 258715.430 us; speedup vs baseline: 1.0054x; 1.0054x over previous
//
#include <hip/hip_runtime.h>
#include <cstddef>

#define NSTEP 4096

// All device pointers the step kernel needs, passed by value.
struct Params {
  const float* xn;        // (4096, 64) normalized input
  const float* w_ih[4];
  const float* w_hh[4];
  const float* b_ih[4];
  const float* b_hh[4];
  float* h[4];            // double buffers: h[l] holds 2*H_l floats, parity t&1
  float* c[4];            // single buffer per layer
  float* out;             // (4096, 256) flat
  int s;                  // launch index
};

// BatchNorm1d over timestep channels: per t, stats over (B=4, F=64) = 256 vals.
__global__ __launch_bounds__(256) void bn_kernel(const float* __restrict__ x,
                                                 const float* __restrict__ bn_w,
                                                 const float* __restrict__ bn_b,
                                                 float* __restrict__ xn)
{
  const int t   = blockIdx.x;        // 0..1023
  const int tid = threadIdx.x;       // 256 = B*F
  const int b   = tid >> 6;
  const int f   = tid & 63;
  const float v = x[((size_t)b * 1024 + t) * 64 + f];
  float s = v, ss = v * v;
  #pragma unroll
  for (int off = 32; off > 0; off >>= 1) {
    s  += __shfl_down(s, off);
    ss += __shfl_down(ss, off);
  }
  __shared__ float sh[8];
  const int w = tid >> 6;
  if ((tid & 63) == 0) { sh[w] = s; sh[4 + w] = ss; }
  __syncthreads();
  const float S    = sh[0] + sh[1] + sh[2] + sh[3];
  const float SS   = sh[4] + sh[5] + sh[6] + sh[7];
  const float mean = S * (1.0f / 256.0f);
  const float var  = SS * (1.0f / 256.0f) - mean * mean;  // biased, matches jnp.var
  const float inv  = rsqrtf(var + 1e-5f);
  const float scale = bn_w[t] * inv;
  const float shift = bn_b[t] - mean * scale;
  // scan order: step index = b*1024 + t
  xn[((size_t)b * 1024 + t) * 64 + f] = v * scale + shift;
}

// One launch = one pipeline slot: L1 does step s, L2 step s-1, L3 s-2, L4 s-3.
// One wave per h-index; the wave computes all 4 gate rows (i,f,g,o) for that
// h, reduces, and lane 0 applies activations + state update. No LDS needed.
__global__ __launch_bounds__(256) void step_kernel(Params p)
{
  const int lane = threadIdx.x & 63;
  const int W = blockIdx.x * 4 + (threadIdx.x >> 6);  // global wave id, 0..3839

  int layer, h, H, IN, t;
  if (W < 2048)      { layer = 0; h = W;        H = 2048; IN = 64;   t = p.s;     }
  else if (W < 3072) { layer = 1; h = W - 2048; H = 1024; IN = 2048; t = p.s - 1; }
  else if (W < 3584) { layer = 2; h = W - 3072; H = 512;  IN = 1024; t = p.s - 2; }
  else               { layer = 3; h = W - 3584; H = 256;  IN = 512;  t = p.s - 3; }
  if (t < 0 || t >= NSTEP) return;

  const float* xin;
  if (layer == 0) xin = p.xn + (size_t)t * 64;
  else            xin = p.h[layer - 1] + (size_t)(t & 1) * IN;  // prev layer, same step
  const float* hprev = p.h[layer] + (size_t)((t + 1) & 1) * H;  // own layer, step t-1
  float*       hout  = p.h[layer] + (size_t)(t & 1) * H;
  const float* wih = p.w_ih[layer];
  const float* whh = p.w_hh[layer];

  float acc[4];
  #pragma unroll
  for (int g = 0; g < 4; ++g) {
    const size_t r = (size_t)g * H + h;   // PyTorch gate order: i, f, g, o
    const float* wi = wih + r * IN;
    const float* wh = whh + r * (size_t)H;
    float a = 0.0f;
    for (int k = lane; k < IN; k += 64) a += wi[k] * xin[k];
    for (int k = lane; k < H;  k += 64) a += wh[k] * hprev[k];
    acc[g] = a;
  }
  #pragma unroll
  for (int off = 32; off > 0; off >>= 1) {
    #pragma unroll
    for (int g = 0; g < 4; ++g) acc[g] += __shfl_down(acc[g], off);
  }
  if (lane == 0) {
    const float* bi = p.b_ih[layer];
    const float* bh = p.b_hh[layer];
    const float gi = acc[0] + bi[h]         + bh[h];
    const float gf = acc[1] + bi[H + h]     + bh[H + h];
    const float gg = acc[2] + bi[2 * H + h] + bh[2 * H + h];
    const float go = acc[3] + bi[3 * H + h] + bh[3 * H + h];
    const float ig = 1.0f / (1.0f + expf(-gi));
    const float fg = 1.0f / (1.0f + expf(-gf));
    const float og = 1.0f / (1.0f + expf(-go));
    const float gt = tanhf(gg);
    const float cn = fg * p.c[layer][h] + ig * gt;
    const float hn = og * tanhf(cn);
    p.c[layer][h] = cn;
    hout[h] = hn;
    if (layer == 3) p.out[(size_t)t * 256 + h] = hn;
  }
}

extern "C" void kernel_launch(void* const* d_in, const int* in_sizes, int n_in,
                              void* d_out, int out_size, void* d_ws, size_t ws_size,
                              hipStream_t stream)
{
  Params p;
  const float* x    = (const float*)d_in[0];
  const float* bn_w = (const float*)d_in[1];
  const float* bn_b = (const float*)d_in[2];
  for (int l = 0; l < 4; ++l) {
    p.w_ih[l] = (const float*)d_in[3 + 4 * l];
    p.w_hh[l] = (const float*)d_in[4 + 4 * l];
    p.b_ih[l] = (const float*)d_in[5 + 4 * l];
    p.b_hh[l] = (const float*)d_in[6 + 4 * l];
  }

  float* ws = (float*)d_ws;
  float* xn = ws;                    // 4096*64 floats
  float* st = ws + (size_t)4096 * 64;
  p.xn = xn;
  const int Hs[4] = {2048, 1024, 512, 256};
  float* cur = st;
  for (int l = 0; l < 4; ++l) { p.h[l] = cur; cur += 2 * Hs[l]; }
  for (int l = 0; l < 4; ++l) { p.c[l] = cur; cur += Hs[l]; }
  p.out = (float*)d_out;

  const size_t state_bytes = (size_t)(cur - st) * sizeof(float);
  hipMemsetAsync(st, 0, state_bytes, stream);          // zero h/c each call

  bn_kernel<<<1024, 256, 0, stream>>>(x, bn_w, bn_b, xn);

  for (int s = 0; s < NSTEP + 3; ++s) {
    p.s = s;
    step_kernel<<<960, 256, 0, stream>>>(p);
  }
}